// Round 11
// baseline (114.285 us; speedup 1.0000x reference)
//
#include <hip/hip_runtime.h>
#include <hip/hip_bf16.h>
#include <stdint.h>

typedef unsigned short u16;
typedef __attribute__((ext_vector_type(8))) short short8;   // 8 bf16 (4 VGPRs)
typedef __attribute__((ext_vector_type(4))) short short4v;  // 4 bf16 (2 VGPRs)
typedef __attribute__((ext_vector_type(4))) float f32x4;    // MFMA C/D

#define NB 2
#define NC 128
#define NHD 4      // heads
#define HD 32      // head dim
#define NN 3136    // H*W
#define NA 49      // agent tokens
#define NSPLIT 8   // flash K-split (8 -> 1600 blocks, ~6.25/CU)
#define NTILE 25
#define SCALE 0.17677669529663687f  // 1/sqrt(32)
#define LOG2E 1.4426950408889634f
#define QSC (SCALE * LOG2E)

__device__ inline u16 bfb(float f) {
    __hip_bfloat16 h = __float2bfloat16(f);
    return *(u16*)&h;
}
__device__ inline float b2f(u16 w) {
    return __uint_as_float(((uint32_t)w) << 16);
}
__device__ inline short4v pack4(float a, float b, float c, float d) {
    union { short4v s; __hip_bfloat162 h[2]; } u;
    u.h[0] = __float22bfloat162_rn(make_float2(a, b));
    u.h[1] = __float22bfloat162_rn(make_float2(c, d));
    return u.s;
}
__device__ inline short8 pack8(float4 a, float4 b) {
    union { short8 s; __hip_bfloat162 h[4]; } u;
    u.h[0] = __float22bfloat162_rn(make_float2(a.x, a.y));
    u.h[1] = __float22bfloat162_rn(make_float2(a.z, a.w));
    u.h[2] = __float22bfloat162_rn(make_float2(b.x, b.y));
    u.h[3] = __float22bfloat162_rn(make_float2(b.z, b.w));
    return u.s;
}
__device__ inline float ldf(const void* p, size_t i, int f) {
    return f ? b2f(((const u16*)p)[i]) : ((const float*)p)[i];
}
__device__ inline void gld16(const u16* g, u16* l) {
    __builtin_amdgcn_global_load_lds(
        (__attribute__((address_space(1))) void*)(g),
        (__attribute__((address_space(3))) void*)(l), 16, 0, 0);
}
__device__ inline void stage8k(const u16* g, u16* lds, int w, int lane) {
    gld16(g + (size_t)(w * 64 + lane) * 8,       lds + (size_t)w * 512);
    gld16(g + (size_t)(256 + w * 64 + lane) * 8, lds + 2048 + (size_t)w * 512);
}
// per-block dtype detect (deterministic; all 256 threads participate)
__device__ inline int detect_local(const u16* raw, int t) {
    __shared__ int cnt;
    if (t == 0) cnt = 0;
    __syncthreads();
    float a = fabsf(b2f(raw[t * 97]));
    if (a >= 1e-4f && a <= 100.0f) atomicAdd(&cnt, 1);
    __syncthreads();
    return cnt >= 230;
}

// ---------------------------------------------------------------------------
// small prep: [0,64) wproj -> wps (granule-transposed bf16); [64,66) biases
// (+flag); [66,145) agent 8x8 pool from RAW x -> agb/agT.
__global__ __launch_bounds__(256) void k_prep(const void* __restrict__ xr,
                                              const void* __restrict__ wp,
                                              const void* __restrict__ bp,
                                              const void* __restrict__ g,
                                              const void* __restrict__ bb,
                                              u16* __restrict__ wps,
                                              float* __restrict__ bgb,
                                              u16* __restrict__ agb,
                                              u16* __restrict__ agT,
                                              int* __restrict__ flagOut) {
    int bx = blockIdx.x, t = threadIdx.x;
    int f = detect_local((const u16*)xr, t);
    if (bx < 64) {
        int i = bx * 256 + t;
        int o = i >> 7, c = i & 127;
        wps[(((o >> 4) * 16 + (c >> 3)) * 16 + (o & 15)) * 8 + (c & 7)] =
            bfb(ldf(wp, i, f));
    } else if (bx < 66) {
        int i = (bx - 64) * 256 + t;
        if (i < 128)      bgb[i] = ldf(bp, i, f);
        else if (i < 256) bgb[i] = ldf(g, i - 128, f);
        else if (i < 384) bgb[i] = ldf(bb, i - 256, f);
        if (bx == 64 && t == 0) *flagOut = f;
    } else {
        int idx = (bx - 66) * 256 + t;
        const int NPOOL = NB * NC * NA;   // 12544
        if (idx < NPOOL) {
            int b = idx / (NC * NA);
            int r = idx % (NC * NA);
            int c = r / NA;
            int a = r % NA;
            int ai = a / 7, aj = a % 7;
            size_t base = ((size_t)(b * NC + c)) * NN + ai * 8 * 56 + aj * 8;
            float s = 0.f;
            if (f) {
                const u16* xp = (const u16*)xr + base;
#pragma unroll
                for (int uu = 0; uu < 8; ++uu) {
                    ushort4 a0 = *(const ushort4*)&xp[uu * 56];
                    ushort4 a1 = *(const ushort4*)&xp[uu * 56 + 4];
                    s += b2f(a0.x) + b2f(a0.y) + b2f(a0.z) + b2f(a0.w)
                       + b2f(a1.x) + b2f(a1.y) + b2f(a1.z) + b2f(a1.w);
                }
            } else {
                const float* xp = (const float*)xr + base;
#pragma unroll
                for (int uu = 0; uu < 8; ++uu) {
                    float4 v0 = *(const float4*)&xp[uu * 56];
                    float4 v1 = *(const float4*)&xp[uu * 56 + 4];
                    s += v0.x + v0.y + v0.z + v0.w + v1.x + v1.y + v1.z + v1.w;
                }
            }
            int h = c >> 5, d = c & 31;
            int bh = b * NHD + h;
            u16 val = bfb(s * (1.f / 64.f));
            agb[bh * 2048 + a * 32 + d] = val;
            agT[bh * 2048 + d * 64 + a] = val;
        } else {
            int j = idx - NPOOL;
            if (j < 3840) {
                int bh = j / 480, rem = j % 480;
                int a = 49 + rem / 32, d = rem % 32;
                agb[bh * 2048 + a * 32 + d] = 0;
            } else if (j < 7680) {
                j -= 3840;
                int bh = j / 480, rem = j % 480;
                int a = 49 + rem / 32, d = rem % 32;
                agT[bh * 2048 + d * 64 + a] = 0;
            }
        }
    }
}

// ---------------------------------------------------------------------------
// QKV + fused stage-1, reading RAW x and RAW wqkv. In-block LDS bounce.
// grid (49, 6, NB) x 256.
__global__ __launch_bounds__(256, 4) void k_qkv_s1(const void* __restrict__ xr,
                                                   const void* __restrict__ wq,
                                                   const u16* __restrict__ agb,
                                                   const u16* __restrict__ agT,
                                                   u16* __restrict__ kbf,
                                                   u16* __restrict__ vtb,
                                                   u16* __restrict__ qcb) {
    __shared__ __align__(16) u16 xs[8192];      // granule B-tile (16 KB)
    __shared__ __align__(16) u16 tmpq[8320];    // tmp 128x65; qtile overlays
    u16* qtile = tmpq;                          // 2*64*40 = 5120 (after tmp dead)
    int t = threadIdx.x;
    int f = detect_local((const u16*)xr, t);
    int B = blockIdx.z;
    int n0 = blockIdx.x * 64;
    const f32x4 z = {0.f, 0.f, 0.f, 0.f};
    // ---- stage A: raw x rows -> tmp[c][n] (pad 65) ----
    {
        int c = t >> 1, half = t & 1;
        size_t base = ((size_t)(B * 128 + c)) * NN + n0 + half * 32;
        u16 vals[32];
        if (f) {
            const u16* xp = (const u16*)xr + base;
#pragma unroll
            for (int j = 0; j < 4; ++j) {
                short8 v = *(const short8*)&xp[j * 8];
#pragma unroll
                for (int e = 0; e < 8; ++e) vals[j * 8 + e] = (u16)v[e];
            }
        } else {
            const float* xp = (const float*)xr + base;
#pragma unroll
            for (int j = 0; j < 8; ++j) {
                float4 v = *(const float4*)&xp[j * 4];
                vals[j * 4 + 0] = bfb(v.x); vals[j * 4 + 1] = bfb(v.y);
                vals[j * 4 + 2] = bfb(v.z); vals[j * 4 + 3] = bfb(v.w);
            }
        }
#pragma unroll
        for (int i = 0; i < 32; ++i)
            tmpq[c * 65 + half * 32 + i] = vals[i];
    }
    __syncthreads();
    // ---- stage B: gather -> xs granule layout [g*64+n]*8 ----
#pragma unroll
    for (int k = 0; k < 4; ++k) {
        int j = k * 256 + t;
        int gg = j >> 6, n = j & 63;
        short8 o;
#pragma unroll
        for (int ci = 0; ci < 8; ++ci) o[ci] = (short)tmpq[(gg * 8 + ci) * 65 + n];
        *(short8*)&xs[(size_t)j * 8] = o;
    }
    int w = t >> 6, lane = t & 63;
    int c = lane & 15, u = lane >> 4;
    int o0 = blockIdx.y * 64 + w * 16;
    // ---- A-frags from raw wqkv ----
    short8 af[4];
    if (f) {
        const u16* wqp = (const u16*)wq + (size_t)(o0 + c) * 128 + u * 8;
#pragma unroll
        for (int kt = 0; kt < 4; ++kt) af[kt] = *(const short8*)&wqp[kt * 32];
    } else {
        const float* wqp = (const float*)wq + (size_t)(o0 + c) * 128 + u * 8;
#pragma unroll
        for (int kt = 0; kt < 4; ++kt)
            af[kt] = pack8(*(const float4*)&wqp[kt * 32],
                           *(const float4*)&wqp[kt * 32 + 4]);
    }
    int tq = o0 >> 7, h = (o0 >> 5) & 3, d0 = (o0 & 31) + u * 4;
    size_t bh = (size_t)B * NHD + h;
    __syncthreads();   // xs ready; tmp dead -> qtile region writable
#pragma unroll
    for (int nt = 0; nt < 4; ++nt) {
        int n = n0 + nt * 16 + c;
        f32x4 acc = z;
        acc = __builtin_amdgcn_mfma_f32_16x16x32_bf16(af[0],
            *(const short8*)&xs[((0 * 4 + u) * 64 + nt * 16 + c) * 8], acc, 0, 0, 0);
        acc = __builtin_amdgcn_mfma_f32_16x16x32_bf16(af[1],
            *(const short8*)&xs[((1 * 4 + u) * 64 + nt * 16 + c) * 8], acc, 0, 0, 0);
        acc = __builtin_amdgcn_mfma_f32_16x16x32_bf16(af[2],
            *(const short8*)&xs[((2 * 4 + u) * 64 + nt * 16 + c) * 8], acc, 0, 0, 0);
        acc = __builtin_amdgcn_mfma_f32_16x16x32_bf16(af[3],
            *(const short8*)&xs[((3 * 4 + u) * 64 + nt * 16 + c) * 8], acc, 0, 0, 0);
        if (tq == 0) {
            int hl = (o0 >> 5) & 1;
            *(short4v*)&qtile[(hl * 64 + nt * 16 + c) * 40 + d0] =
                pack4(acc[0] * QSC, acc[1] * QSC, acc[2] * QSC, acc[3] * QSC);
        } else if (tq == 1) {
            int tile = n >> 7, sub = (n >> 4) & 7, key = n & 15;
            int dg = d0 >> 3, wi = d0 & 7;
            size_t kb0 = (((size_t)bh * NTILE + tile) * 8 + sub) * 4 + dg;
            *(short4v*)&kbf[kb0 * 128 + key * 8 + wi] =
                pack4(acc[0], acc[1], acc[2], acc[3]);
        } else {
            int tile = n >> 7, kt2 = n & 127;
            int sub = kt2 >> 4, uu = (kt2 >> 2) & 3, jj = n & 3;
            size_t vb0 = ((size_t)bh * NTILE + tile) * 4096 + sub * 512 + uu * 128 + jj;
#pragma unroll
            for (int r = 0; r < 4; ++r)
                vtb[vb0 + (d0 + r) * 4] = bfb(acc[r]);
        }
    }
    if (blockIdx.y < 2) {
        __syncthreads();
        // stage1: 8 tiles (2 heads x 4 row-groups); wave w takes tiles w, w+4
#pragma unroll
        for (int tt = w; tt < 8; tt += 4) {
            int hl2 = tt >> 2, r0 = (tt & 3) * 16;
            int hg = blockIdx.y * 2 + hl2;
            size_t bh2 = (size_t)B * NHD + hg;
            const u16* aB = agb + bh2 * 2048;
            const u16* aT = agT + bh2 * 2048;
            short8 qf = *(const short8*)&qtile[(hl2 * 64 + r0 + c) * 40 + u * 8];
            f32x4 st[4];
#pragma unroll
            for (int t2 = 0; t2 < 4; ++t2) {
                short8 afr = *(const short8*)&aB[(t2 * 16 + c) * 32 + u * 8];
                st[t2] = __builtin_amdgcn_mfma_f32_16x16x32_bf16(afr, qf, z, 0, 0, 0);
            }
            float e[4][4];
            float lsum = 0.f;
#pragma unroll
            for (int t2 = 0; t2 < 4; ++t2)
#pragma unroll
                for (int r = 0; r < 4; ++r) {
                    float v = __builtin_amdgcn_exp2f(st[t2][r]);
                    if (t2 == 3 && !(u == 0 && r == 0)) v = 0.f;   // agents >= 49
                    e[t2][r] = v;
                    lsum += v;
                }
            lsum += __shfl_xor(lsum, 16);
            lsum += __shfl_xor(lsum, 32);
            float linv = 1.f / lsum;
            f32x4 qlo = z, qhi = z;
#pragma unroll
            for (int t2 = 0; t2 < 4; ++t2) {
                short4v pf = pack4(e[t2][0] * linv, e[t2][1] * linv,
                                   e[t2][2] * linv, e[t2][3] * linv);
                short4v alo = *(const short4v*)&aT[c * 64 + t2 * 16 + u * 4];
                short4v ahi = *(const short4v*)&aT[(c + 16) * 64 + t2 * 16 + u * 4];
                qlo = __builtin_amdgcn_mfma_f32_16x16x16bf16_1k(alo, pf, qlo, 0, 0, 0);
                qhi = __builtin_amdgcn_mfma_f32_16x16x16bf16_1k(ahi, pf, qhi, 0, 0, 0);
            }
            u16* dst = &qcb[(bh2 * NN + n0 + r0 + c) * HD];
            *(short4v*)&dst[u * 4]      = pack4(qlo[0] * QSC, qlo[1] * QSC, qlo[2] * QSC, qlo[3] * QSC);
            *(short4v*)&dst[16 + u * 4] = pack4(qhi[0] * QSC, qhi[1] * QSC, qhi[2] * QSC, qhi[3] * QSC);
        }
    }
}

// ---------------------------------------------------------------------------
// stage 2 flash: LDS dbuf via global_load_lds; K granule-fragmented; l via
// ones-MFMA. NSPLIT=8 -> grid (25, 32, NB) = 1600 blocks (~6.25/CU) for
// latency hiding across blocks. launch_bounds(256,4).
__global__ __launch_bounds__(256, 4) void k_flash4(const u16* __restrict__ qc,
                                                   const u16* __restrict__ kb,
                                                   const u16* __restrict__ vt,
                                                   u16* __restrict__ opb,
                                                   float* __restrict__ lp) {
    __shared__ __align__(16) u16 Ks[2][4096];
    __shared__ __align__(16) u16 Vs[2][4096];
    int b = blockIdx.z;
    int h = blockIdx.y & 3;
    int s = blockIdx.y >> 2;
    int w = threadIdx.x >> 6, lane = threadIdx.x & 63;
    int c = lane & 15, u = lane >> 4;
    int qa = blockIdx.x * 128 + w * 32;
    int qbr = qa + 16;
    if (qa  > NN - 16) qa  = NN - 16;
    if (qbr > NN - 16) qbr = NN - 16;
    size_t bh = (size_t)b * NHD + h;
    const u16* kg = kb + bh * (size_t)NTILE * 4096;
    const u16* vg = vt + bh * (size_t)NTILE * 4096;
    short8 qfA = *(const short8*)(qc + (bh * NN + qa  + c) * HD + u * 8);
    short8 qfB = *(const short8*)(qc + (bh * NN + qbr + c) * HD + u * 8);
    const f32x4 z = {0.f, 0.f, 0.f, 0.f};
    short4v ones4;
#pragma unroll
    for (int i = 0; i < 4; ++i) ones4[i] = (short)0x3F80;   // bf16 1.0
    f32x4 oA0 = z, oA1 = z, oB0 = z, oB1 = z;
    f32x4 lAa = z, lBa = z;
    int t0 = (s * NTILE) / NSPLIT, t1 = ((s + 1) * NTILE) / NSPLIT;
    stage8k(kg + (size_t)t0 * 4096, &Ks[0][0], w, lane);
    stage8k(vg + (size_t)t0 * 4096, &Vs[0][0], w, lane);
#pragma unroll 1
    for (int t = t0; t < t1; ++t) {
        int buf = (t - t0) & 1;
        __syncthreads();
        if (t + 1 < t1) {
            stage8k(kg + (size_t)(t + 1) * 4096, &Ks[buf ^ 1][0], w, lane);
            stage8k(vg + (size_t)(t + 1) * 4096, &Vs[buf ^ 1][0], w, lane);
        }
        const u16* kp = &Ks[buf][0];
        const u16* vp = &Vs[buf][0];
        int kk = t * 128;
        bool tail = (kk + 128 > NN);
#pragma unroll
        for (int sub = 0; sub < 8; ++sub) {
            short8 kf = *(const short8*)(kp + ((sub * 4 + u) * 16 + c) * 8);
            f32x4 sA = __builtin_amdgcn_mfma_f32_16x16x32_bf16(kf, qfA, z, 0, 0, 0);
            f32x4 sB = __builtin_amdgcn_mfma_f32_16x16x32_bf16(kf, qfB, z, 0, 0, 0);
            float eA[4], eB[4];
#pragma unroll
            for (int r = 0; r < 4; ++r) {
                eA[r] = __builtin_amdgcn_exp2f(sA[r]);
                eB[r] = __builtin_amdgcn_exp2f(sB[r]);
            }
            if (tail) {
#pragma unroll
                for (int r = 0; r < 4; ++r)
                    if (kk + sub * 16 + u * 4 + r >= NN) { eA[r] = 0.f; eB[r] = 0.f; }
            }
            short4v pA = pack4(eA[0], eA[1], eA[2], eA[3]);
            short4v pB = pack4(eB[0], eB[1], eB[2], eB[3]);
            short4v va = *(const short4v*)(vp + sub * 512 + u * 128 + c * 4);
            short4v vb = *(const short4v*)(vp + sub * 512 + u * 128 + (c + 16) * 4);
            oA0 = __builtin_amdgcn_mfma_f32_16x16x16bf16_1k(va, pA, oA0, 0, 0, 0);
            oA1 = __builtin_amdgcn_mfma_f32_16x16x16bf16_1k(vb, pA, oA1, 0, 0, 0);
            oB0 = __builtin_amdgcn_mfma_f32_16x16x16bf16_1k(va, pB, oB0, 0, 0, 0);
            oB1 = __builtin_amdgcn_mfma_f32_16x16x16bf16_1k(vb, pB, oB1, 0, 0, 0);
            lAa = __builtin_amdgcn_mfma_f32_16x16x16bf16_1k(ones4, pA, lAa, 0, 0, 0);
            lBa = __builtin_amdgcn_mfma_f32_16x16x16bf16_1k(ones4, pB, lBa, 0, 0, 0);
        }
    }
    float lA = lAa[0], lB = lBa[0];   // all rows identical (A = ones)
    float iA = 1.f / lA, iB = 1.f / lB;
    u16* oba = opb + (((size_t)(s * NB + b)) * NN + qa + c) * NC + h * HD;
    *(short4v*)&oba[u * 4]      = pack4(oA0[0] * iA, oA0[1] * iA, oA0[2] * iA, oA0[3] * iA);
    *(short4v*)&oba[16 + u * 4] = pack4(oA1[0] * iA, oA1[1] * iA, oA1[2] * iA, oA1[3] * iA);
    u16* obb = opb + (((size_t)(s * NB + b)) * NN + qbr + c) * NC + h * HD;
    *(short4v*)&obb[u * 4]      = pack4(oB0[0] * iB, oB0[1] * iB, oB0[2] * iB, oB0[3] * iB);
    *(short4v*)&obb[16 + u * 4] = pack4(oB1[0] * iB, oB1[1] * iB, oB1[2] * iB, oB1[3] * iB);
    if (u == 0) {
        lp[(((size_t)(s * NB + b)) * NHD + h) * NN + qa  + c] = lA;
        lp[(((size_t)(s * NB + b)) * NHD + h) * NN + qbr + c] = lB;
    }
}

// ---------------------------------------------------------------------------
// proj + LN via MFMA; 32 KB weight tile staged per block via global_load_lds.
// grid 392 x 256.
__global__ __launch_bounds__(256, 4) void k_proj2(const u16* __restrict__ opb,
                                                  const float* __restrict__ lp,
                                                  const u16* __restrict__ wps,
                                                  const float* __restrict__ bgb,
                                                  void* __restrict__ out,
                                                  const int* __restrict__ flag) {
    __shared__ __align__(16) u16 wl[16384];   // 32 KB staged weights
    __shared__ u16 Af[16 * 136];
    __shared__ float red1[4][16], red2[4][16];
    int bx = blockIdx.x;
    int b = bx >= 196;
    int n0 = (bx - b * 196) * 16;
    int t = threadIdx.x;
#pragma unroll
    for (int i = 0; i < 8; ++i)
        gld16(wps + (size_t)(i * 256 + t) * 8, wl + (size_t)(i * 256 + t) * 8);
    {   // combine: thread t -> row t>>4, channels (t&15)*8..+7
        int row = t >> 4, c8 = (t & 15) * 8;
        int n = n0 + row;
        int hh = c8 >> 5;
        float num[8] = {};
        float den = 0.f;
#pragma unroll
        for (int s = 0; s < NSPLIT; ++s) {
            float ls = lp[(((size_t)(s * NB + b)) * NHD + hh) * NN + n];
            short8 o8 = *(const short8*)&opb[(((size_t)(s * NB + b)) * NN + n) * NC + c8];
            den += ls;
#pragma unroll
            for (int i = 0; i < 8; ++i) num[i] += ls * b2f((u16)o8[i]);
        }
        float inv = 1.f / den;
        u16* dst = &Af[row * 136 + c8];
#pragma unroll
        for (int i = 0; i < 8; i += 2) {
            __hip_bfloat162 p = __float22bfloat162_rn(
                make_float2(num[i] * inv, num[i + 1] * inv));
            *(uint32_t*)&dst[i] = *(uint32_t*)&p;
        }
    }
    __syncthreads();   // drains weight staging + Af writes
    int w = t >> 6, lane = t & 63, c = lane & 15, u = lane >> 4;
    int oA = w * 32 + c, oB = w * 32 + 16 + c;
    const f32x4 z = {0.f, 0.f, 0.f, 0.f};
    f32x4 cA = z, cB = z;
#pragma unroll
    for (int kf = 0; kf < 4; ++kf) {
        short8 a  = *(const short8*)&Af[c * 136 + kf * 32 + u * 8];
        short8 bA = *(const short8*)&wl[(((2 * w) * 16 + kf * 4 + u) * 16 + c) * 8];
        short8 bB = *(const short8*)&wl[(((2 * w + 1) * 16 + kf * 4 + u) * 16 + c) * 8];
        cA = __builtin_amdgcn_mfma_f32_16x16x32_bf16(a, bA, cA, 0, 0, 0);
        cB = __builtin_amdgcn_mfma_f32_16x16x32_bf16(a, bB, cB, 0, 0, 0);
    }
    float bpA = bgb[oA], bpB = bgb[oB];
    float s1[4], s2[4];
#pragma unroll
    for (int r = 0; r < 4; ++r) {
        cA[r] += bpA; cB[r] += bpB;
        s1[r] = cA[r] + cB[r];
        s2[r] = cA[r] * cA[r] + cB[r] * cB[r];
    }
#pragma unroll
    for (int off = 1; off < 16; off <<= 1)
#pragma unroll
        for (int r = 0; r < 4; ++r) {
            s1[r] += __shfl_xor(s1[r], off);
            s2[r] += __shfl_xor(s2[r], off);
        }
    if (c == 0)
#pragma unroll
        for (int r = 0; r < 4; ++r) {
            red1[w][u * 4 + r] = s1[r];
            red2[w][u * 4 + r] = s2[r];
        }
    __syncthreads();
    float gA = bgb[128 + oA], beA = bgb[256 + oA];
    float gB = bgb[128 + oB], beB = bgb[256 + oB];
    float outA[4], outB[4];
#pragma unroll
    for (int r = 0; r < 4; ++r) {
        int row = u * 4 + r;
        float S1 = (red1[0][row] + red1[1][row]) + (red1[2][row] + red1[3][row]);
        float S2 = (red2[0][row] + red2[1][row]) + (red2[2][row] + red2[3][row]);
        float mu = S1 * (1.f / NC);
        float ex = S2 * (1.f / NC);
        float rstd = rsqrtf(ex - mu * mu + 1e-5f);
        outA[r] = (cA[r] - mu) * rstd * gA + beA;
        outB[r] = (cB[r] - mu) * rstd * gB + beB;
    }
    int n = n0 + u * 4;   // 4 consecutive rows per lane
    if (*flag) {
        __hip_bfloat16* ob = (__hip_bfloat16*)out;
        ushort4 sA = make_ushort4(bfb(outA[0]), bfb(outA[1]), bfb(outA[2]), bfb(outA[3]));
        ushort4 sB = make_ushort4(bfb(outB[0]), bfb(outB[1]), bfb(outB[2]), bfb(outB[3]));
        *(ushort4*)&ob[((size_t)(b * NC + oA)) * NN + n] = sA;
        *(ushort4*)&ob[((size_t)(b * NC + oB)) * NN + n] = sB;
    } else {
        float* ob = (float*)out;
        *(float4*)&ob[((size_t)(b * NC + oA)) * NN + n] = make_float4(outA[0], outA[1], outA[2], outA[3]);
        *(float4*)&ob[((size_t)(b * NC + oB)) * NN + n] = make_float4(outB[0], outB[1], outB[2], outB[3]);
    }
}

// ---------------------------------------------------------------------------
extern "C" void kernel_launch(void* const* d_in, const int* in_sizes, int n_in,
                              void* d_out, int out_size, void* d_ws, size_t ws_size,
                              hipStream_t stream) {
    const void* x_raw  = d_in[0];
    const void* wq_raw = d_in[1];
    const void* wp_raw = d_in[2];
    const void* bp_raw = d_in[3];
    const void* lg_raw = d_in[4];
    const void* lb_raw = d_in[5];

    int*   flag = (int*)d_ws;                           // 16 ints
    float* bgb  = (float*)d_ws + 16;                    // 512
    float* lp   = bgb + 512;                            // 8*2*4*3136
    u16*   opb  = (u16*)(lp + (size_t)NSPLIT * NB * NHD * NN);  // 8*2*3136*128
    u16*   wps  = opb + (size_t)NSPLIT * NB * NN * NC;  // 16384
    u16*   kbf  = wps + NC * NC;                        // 25 tiles x 4096 /bh
    u16*   vtb  = kbf + (size_t)NB * NHD * NTILE * 4096;
    u16*   qcb  = vtb + (size_t)NB * NHD * NTILE * 4096;
    u16*   agb  = qcb + (size_t)NB * NHD * NN * HD;     // 16384
    u16*   agT  = agb + NB * NHD * 64 * 32;             // 16384
    // total ~20 MB

    k_prep<<<145, 256, 0, stream>>>(x_raw, wp_raw, bp_raw, lg_raw, lb_raw,
                                    wps, bgb, agb, agT, flag);
    k_qkv_s1<<<dim3(NN / 64, 6, NB), 256, 0, stream>>>(x_raw, wq_raw, agb, agT,
                                                       kbf, vtb, qcb);
    k_flash4<<<dim3(25, NHD * NSPLIT, NB), 256, 0, stream>>>(qcb, kbf, vtb, opb, lp);
    k_proj2<<<392, 256, 0, stream>>>(opb, lp, wps, bgb, d_out, flag);
}

// Round 12
// 112.583 us; speedup vs baseline: 1.0151x; 1.0151x over previous
//
#include <hip/hip_runtime.h>
#include <hip/hip_bf16.h>
#include <stdint.h>

typedef unsigned short u16;
typedef __attribute__((ext_vector_type(8))) short short8;   // 8 bf16 (4 VGPRs)
typedef __attribute__((ext_vector_type(4))) short short4v;  // 4 bf16 (2 VGPRs)
typedef __attribute__((ext_vector_type(4))) float f32x4;    // MFMA C/D

#define NB 2
#define NC 128
#define NHD 4      // heads
#define HD 32      // head dim
#define NN 3136    // H*W
#define NA 49      // agent tokens
#define NSPLIT 4   // flash K-split
#define NTILE 25
#define SCALE 0.17677669529663687f  // 1/sqrt(32)
#define LOG2E 1.4426950408889634f
#define QSC (SCALE * LOG2E)

__device__ inline u16 bfb(float f) {
    __hip_bfloat16 h = __float2bfloat16(f);
    return *(u16*)&h;
}
__device__ inline float b2f(u16 w) {
    return __uint_as_float(((uint32_t)w) << 16);
}
__device__ inline short4v pack4(float a, float b, float c, float d) {
    union { short4v s; __hip_bfloat162 h[2]; } u;
    u.h[0] = __float22bfloat162_rn(make_float2(a, b));
    u.h[1] = __float22bfloat162_rn(make_float2(c, d));
    return u.s;
}
__device__ inline short8 pack8(float4 a, float4 b) {
    union { short8 s; __hip_bfloat162 h[4]; } u;
    u.h[0] = __float22bfloat162_rn(make_float2(a.x, a.y));
    u.h[1] = __float22bfloat162_rn(make_float2(a.z, a.w));
    u.h[2] = __float22bfloat162_rn(make_float2(b.x, b.y));
    u.h[3] = __float22bfloat162_rn(make_float2(b.z, b.w));
    return u.s;
}
__device__ inline float ldf(const void* p, size_t i, int f) {
    return f ? b2f(((const u16*)p)[i]) : ((const float*)p)[i];
}
__device__ inline void gld16(const u16* g, u16* l) {
    __builtin_amdgcn_global_load_lds(
        (__attribute__((address_space(1))) void*)(g),
        (__attribute__((address_space(3))) void*)(l), 16, 0, 0);
}
__device__ inline void stage8k(const u16* g, u16* lds, int w, int lane) {
    gld16(g + (size_t)(w * 64 + lane) * 8,       lds + (size_t)w * 512);
    gld16(g + (size_t)(256 + w * 64 + lane) * 8, lds + 2048 + (size_t)w * 512);
}
// per-block dtype detect (deterministic; all 256 threads participate)
__device__ inline int detect_local(const u16* raw, int t) {
    __shared__ int cnt;
    if (t == 0) cnt = 0;
    __syncthreads();
    float a = fabsf(b2f(raw[t * 97]));
    if (a >= 1e-4f && a <= 100.0f) atomicAdd(&cnt, 1);
    __syncthreads();
    return cnt >= 230;
}

// ---------------------------------------------------------------------------
// small prep: [0,64) wproj -> wps (granule-transposed bf16); [64,66) biases
// (+flag); [66,145) agent 8x8 pool from RAW x -> agb/agT.
__global__ __launch_bounds__(256) void k_prep(const void* __restrict__ xr,
                                              const void* __restrict__ wp,
                                              const void* __restrict__ bp,
                                              const void* __restrict__ g,
                                              const void* __restrict__ bb,
                                              u16* __restrict__ wps,
                                              float* __restrict__ bgb,
                                              u16* __restrict__ agb,
                                              u16* __restrict__ agT,
                                              int* __restrict__ flagOut) {
    int bx = blockIdx.x, t = threadIdx.x;
    int f = detect_local((const u16*)xr, t);
    if (bx < 64) {
        int i = bx * 256 + t;
        int o = i >> 7, c = i & 127;
        wps[(((o >> 4) * 16 + (c >> 3)) * 16 + (o & 15)) * 8 + (c & 7)] =
            bfb(ldf(wp, i, f));
    } else if (bx < 66) {
        int i = (bx - 64) * 256 + t;
        if (i < 128)      bgb[i] = ldf(bp, i, f);
        else if (i < 256) bgb[i] = ldf(g, i - 128, f);
        else if (i < 384) bgb[i] = ldf(bb, i - 256, f);
        if (bx == 64 && t == 0) *flagOut = f;
    } else {
        int idx = (bx - 66) * 256 + t;
        const int NPOOL = NB * NC * NA;   // 12544
        if (idx < NPOOL) {
            int b = idx / (NC * NA);
            int r = idx % (NC * NA);
            int c = r / NA;
            int a = r % NA;
            int ai = a / 7, aj = a % 7;
            size_t base = ((size_t)(b * NC + c)) * NN + ai * 8 * 56 + aj * 8;
            float s = 0.f;
            if (f) {
                const u16* xp = (const u16*)xr + base;
#pragma unroll
                for (int uu = 0; uu < 8; ++uu) {
                    ushort4 a0 = *(const ushort4*)&xp[uu * 56];
                    ushort4 a1 = *(const ushort4*)&xp[uu * 56 + 4];
                    s += b2f(a0.x) + b2f(a0.y) + b2f(a0.z) + b2f(a0.w)
                       + b2f(a1.x) + b2f(a1.y) + b2f(a1.z) + b2f(a1.w);
                }
            } else {
                const float* xp = (const float*)xr + base;
#pragma unroll
                for (int uu = 0; uu < 8; ++uu) {
                    float4 v0 = *(const float4*)&xp[uu * 56];
                    float4 v1 = *(const float4*)&xp[uu * 56 + 4];
                    s += v0.x + v0.y + v0.z + v0.w + v1.x + v1.y + v1.z + v1.w;
                }
            }
            int h = c >> 5, d = c & 31;
            int bh = b * NHD + h;
            u16 val = bfb(s * (1.f / 64.f));
            agb[bh * 2048 + a * 32 + d] = val;
            agT[bh * 2048 + d * 64 + a] = val;
        } else {
            int j = idx - NPOOL;
            if (j < 3840) {
                int bh = j / 480, rem = j % 480;
                int a = 49 + rem / 32, d = rem % 32;
                agb[bh * 2048 + a * 32 + d] = 0;
            } else if (j < 7680) {
                j -= 3840;
                int bh = j / 480, rem = j % 480;
                int a = 49 + rem / 32, d = rem % 32;
                agT[bh * 2048 + d * 64 + a] = 0;
            }
        }
    }
}

// ---------------------------------------------------------------------------
// QKV + fused stage-1, reading RAW x and RAW wqkv. In-block LDS bounce with
// VECTORIZED stage-A writes (stride-72 rows: 16B-aligned, even bank spread ->
// ds_write_b128 at the 8-clk minimum). grid (49, 6, NB) x 256.
__global__ __launch_bounds__(256, 4) void k_qkv_s1(const void* __restrict__ xr,
                                                   const void* __restrict__ wq,
                                                   const u16* __restrict__ agb,
                                                   const u16* __restrict__ agT,
                                                   u16* __restrict__ kbf,
                                                   u16* __restrict__ vtb,
                                                   u16* __restrict__ qcb) {
    __shared__ __align__(16) u16 xs[8192];      // granule B-tile (16 KB)
    __shared__ __align__(16) u16 tmpq[9216];    // tmp 128x72; qtile overlays
    u16* qtile = tmpq;                          // 2*64*40 = 5120 (after tmp dead)
    int t = threadIdx.x;
    int f = detect_local((const u16*)xr, t);
    int B = blockIdx.z;
    int n0 = blockIdx.x * 64;
    const f32x4 z = {0.f, 0.f, 0.f, 0.f};
    // ---- stage A: raw x rows -> tmp[c][n] (stride 72, b128 writes) ----
    {
        int c = t >> 1, half = t & 1;
        size_t base = ((size_t)(B * 128 + c)) * NN + n0 + half * 32;
        short8 v8[4];
        if (f) {
            const u16* xp = (const u16*)xr + base;
#pragma unroll
            for (int j = 0; j < 4; ++j) v8[j] = *(const short8*)&xp[j * 8];
        } else {
            const float* xp = (const float*)xr + base;
#pragma unroll
            for (int j = 0; j < 4; ++j)
                v8[j] = pack8(*(const float4*)&xp[j * 8],
                              *(const float4*)&xp[j * 8 + 4]);
        }
        u16* dst = &tmpq[c * 72 + half * 32];
#pragma unroll
        for (int j = 0; j < 4; ++j) *(short8*)&dst[j * 8] = v8[j];
    }
    __syncthreads();
    // ---- stage B: gather -> xs granule layout [g*64+n]*8 ----
#pragma unroll
    for (int k = 0; k < 4; ++k) {
        int j = k * 256 + t;
        int gg = j >> 6, n = j & 63;
        short8 o;
#pragma unroll
        for (int ci = 0; ci < 8; ++ci) o[ci] = (short)tmpq[(gg * 8 + ci) * 72 + n];
        *(short8*)&xs[(size_t)j * 8] = o;
    }
    int w = t >> 6, lane = t & 63;
    int c = lane & 15, u = lane >> 4;
    int o0 = blockIdx.y * 64 + w * 16;
    // ---- A-frags from raw wqkv ----
    short8 af[4];
    if (f) {
        const u16* wqp = (const u16*)wq + (size_t)(o0 + c) * 128 + u * 8;
#pragma unroll
        for (int kt = 0; kt < 4; ++kt) af[kt] = *(const short8*)&wqp[kt * 32];
    } else {
        const float* wqp = (const float*)wq + (size_t)(o0 + c) * 128 + u * 8;
#pragma unroll
        for (int kt = 0; kt < 4; ++kt)
            af[kt] = pack8(*(const float4*)&wqp[kt * 32],
                           *(const float4*)&wqp[kt * 32 + 4]);
    }
    int tq = o0 >> 7, h = (o0 >> 5) & 3, d0 = (o0 & 31) + u * 4;
    size_t bh = (size_t)B * NHD + h;
    __syncthreads();   // xs ready; tmp dead -> qtile region writable
#pragma unroll
    for (int nt = 0; nt < 4; ++nt) {
        int n = n0 + nt * 16 + c;
        f32x4 acc = z;
        acc = __builtin_amdgcn_mfma_f32_16x16x32_bf16(af[0],
            *(const short8*)&xs[((0 * 4 + u) * 64 + nt * 16 + c) * 8], acc, 0, 0, 0);
        acc = __builtin_amdgcn_mfma_f32_16x16x32_bf16(af[1],
            *(const short8*)&xs[((1 * 4 + u) * 64 + nt * 16 + c) * 8], acc, 0, 0, 0);
        acc = __builtin_amdgcn_mfma_f32_16x16x32_bf16(af[2],
            *(const short8*)&xs[((2 * 4 + u) * 64 + nt * 16 + c) * 8], acc, 0, 0, 0);
        acc = __builtin_amdgcn_mfma_f32_16x16x32_bf16(af[3],
            *(const short8*)&xs[((3 * 4 + u) * 64 + nt * 16 + c) * 8], acc, 0, 0, 0);
        if (tq == 0) {
            int hl = (o0 >> 5) & 1;
            *(short4v*)&qtile[(hl * 64 + nt * 16 + c) * 40 + d0] =
                pack4(acc[0] * QSC, acc[1] * QSC, acc[2] * QSC, acc[3] * QSC);
        } else if (tq == 1) {
            int tile = n >> 7, sub = (n >> 4) & 7, key = n & 15;
            int dg = d0 >> 3, wi = d0 & 7;
            size_t kb0 = (((size_t)bh * NTILE + tile) * 8 + sub) * 4 + dg;
            *(short4v*)&kbf[kb0 * 128 + key * 8 + wi] =
                pack4(acc[0], acc[1], acc[2], acc[3]);
        } else {
            int tile = n >> 7, kt2 = n & 127;
            int sub = kt2 >> 4, uu = (kt2 >> 2) & 3, jj = n & 3;
            size_t vb0 = ((size_t)bh * NTILE + tile) * 4096 + sub * 512 + uu * 128 + jj;
#pragma unroll
            for (int r = 0; r < 4; ++r)
                vtb[vb0 + (d0 + r) * 4] = bfb(acc[r]);
        }
    }
    if (blockIdx.y < 2) {
        __syncthreads();
        // stage1: 8 tiles (2 heads x 4 row-groups); wave w takes tiles w, w+4
#pragma unroll
        for (int tt = w; tt < 8; tt += 4) {
            int hl2 = tt >> 2, r0 = (tt & 3) * 16;
            int hg = blockIdx.y * 2 + hl2;
            size_t bh2 = (size_t)B * NHD + hg;
            const u16* aB = agb + bh2 * 2048;
            const u16* aT = agT + bh2 * 2048;
            short8 qf = *(const short8*)&qtile[(hl2 * 64 + r0 + c) * 40 + u * 8];
            f32x4 st[4];
#pragma unroll
            for (int t2 = 0; t2 < 4; ++t2) {
                short8 afr = *(const short8*)&aB[(t2 * 16 + c) * 32 + u * 8];
                st[t2] = __builtin_amdgcn_mfma_f32_16x16x32_bf16(afr, qf, z, 0, 0, 0);
            }
            float e[4][4];
            float lsum = 0.f;
#pragma unroll
            for (int t2 = 0; t2 < 4; ++t2)
#pragma unroll
                for (int r = 0; r < 4; ++r) {
                    float v = __builtin_amdgcn_exp2f(st[t2][r]);
                    if (t2 == 3 && !(u == 0 && r == 0)) v = 0.f;   // agents >= 49
                    e[t2][r] = v;
                    lsum += v;
                }
            lsum += __shfl_xor(lsum, 16);
            lsum += __shfl_xor(lsum, 32);
            float linv = 1.f / lsum;
            f32x4 qlo = z, qhi = z;
#pragma unroll
            for (int t2 = 0; t2 < 4; ++t2) {
                short4v pf = pack4(e[t2][0] * linv, e[t2][1] * linv,
                                   e[t2][2] * linv, e[t2][3] * linv);
                short4v alo = *(const short4v*)&aT[c * 64 + t2 * 16 + u * 4];
                short4v ahi = *(const short4v*)&aT[(c + 16) * 64 + t2 * 16 + u * 4];
                qlo = __builtin_amdgcn_mfma_f32_16x16x16bf16_1k(alo, pf, qlo, 0, 0, 0);
                qhi = __builtin_amdgcn_mfma_f32_16x16x16bf16_1k(ahi, pf, qhi, 0, 0, 0);
            }
            u16* dst = &qcb[(bh2 * NN + n0 + r0 + c) * HD];
            *(short4v*)&dst[u * 4]      = pack4(qlo[0] * QSC, qlo[1] * QSC, qlo[2] * QSC, qlo[3] * QSC);
            *(short4v*)&dst[16 + u * 4] = pack4(qhi[0] * QSC, qhi[1] * QSC, qhi[2] * QSC, qhi[3] * QSC);
        }
    }
}

// ---------------------------------------------------------------------------
// stage 2 flash: LDS dbuf via global_load_lds; K granule-fragmented; l via
// ones-MFMA. grid (25, NHD*NSPLIT, NB) x 256.
__global__ __launch_bounds__(256, 4) void k_flash4(const u16* __restrict__ qc,
                                                   const u16* __restrict__ kb,
                                                   const u16* __restrict__ vt,
                                                   u16* __restrict__ opb,
                                                   float* __restrict__ lp) {
    __shared__ __align__(16) u16 Ks[2][4096];
    __shared__ __align__(16) u16 Vs[2][4096];
    int b = blockIdx.z;
    int h = blockIdx.y & 3;
    int s = blockIdx.y >> 2;
    int w = threadIdx.x >> 6, lane = threadIdx.x & 63;
    int c = lane & 15, u = lane >> 4;
    int qa = blockIdx.x * 128 + w * 32;
    int qbr = qa + 16;
    if (qa  > NN - 16) qa  = NN - 16;
    if (qbr > NN - 16) qbr = NN - 16;
    size_t bh = (size_t)b * NHD + h;
    const u16* kg = kb + bh * (size_t)NTILE * 4096;
    const u16* vg = vt + bh * (size_t)NTILE * 4096;
    short8 qfA = *(const short8*)(qc + (bh * NN + qa  + c) * HD + u * 8);
    short8 qfB = *(const short8*)(qc + (bh * NN + qbr + c) * HD + u * 8);
    const f32x4 z = {0.f, 0.f, 0.f, 0.f};
    short4v ones4;
#pragma unroll
    for (int i = 0; i < 4; ++i) ones4[i] = (short)0x3F80;   // bf16 1.0
    f32x4 oA0 = z, oA1 = z, oB0 = z, oB1 = z;
    f32x4 lAa = z, lBa = z;
    int t0 = (s * NTILE) / NSPLIT, t1 = ((s + 1) * NTILE) / NSPLIT;
    stage8k(kg + (size_t)t0 * 4096, &Ks[0][0], w, lane);
    stage8k(vg + (size_t)t0 * 4096, &Vs[0][0], w, lane);
#pragma unroll 1
    for (int t = t0; t < t1; ++t) {
        int buf = (t - t0) & 1;
        __syncthreads();
        if (t + 1 < t1) {
            stage8k(kg + (size_t)(t + 1) * 4096, &Ks[buf ^ 1][0], w, lane);
            stage8k(vg + (size_t)(t + 1) * 4096, &Vs[buf ^ 1][0], w, lane);
        }
        const u16* kp = &Ks[buf][0];
        const u16* vp = &Vs[buf][0];
        int kk = t * 128;
        bool tail = (kk + 128 > NN);
#pragma unroll
        for (int sub = 0; sub < 8; ++sub) {
            short8 kf = *(const short8*)(kp + ((sub * 4 + u) * 16 + c) * 8);
            f32x4 sA = __builtin_amdgcn_mfma_f32_16x16x32_bf16(kf, qfA, z, 0, 0, 0);
            f32x4 sB = __builtin_amdgcn_mfma_f32_16x16x32_bf16(kf, qfB, z, 0, 0, 0);
            float eA[4], eB[4];
#pragma unroll
            for (int r = 0; r < 4; ++r) {
                eA[r] = __builtin_amdgcn_exp2f(sA[r]);
                eB[r] = __builtin_amdgcn_exp2f(sB[r]);
            }
            if (tail) {
#pragma unroll
                for (int r = 0; r < 4; ++r)
                    if (kk + sub * 16 + u * 4 + r >= NN) { eA[r] = 0.f; eB[r] = 0.f; }
            }
            short4v pA = pack4(eA[0], eA[1], eA[2], eA[3]);
            short4v pB = pack4(eB[0], eB[1], eB[2], eB[3]);
            short4v va = *(const short4v*)(vp + sub * 512 + u * 128 + c * 4);
            short4v vb = *(const short4v*)(vp + sub * 512 + u * 128 + (c + 16) * 4);
            oA0 = __builtin_amdgcn_mfma_f32_16x16x16bf16_1k(va, pA, oA0, 0, 0, 0);
            oA1 = __builtin_amdgcn_mfma_f32_16x16x16bf16_1k(vb, pA, oA1, 0, 0, 0);
            oB0 = __builtin_amdgcn_mfma_f32_16x16x16bf16_1k(va, pB, oB0, 0, 0, 0);
            oB1 = __builtin_amdgcn_mfma_f32_16x16x16bf16_1k(vb, pB, oB1, 0, 0, 0);
            lAa = __builtin_amdgcn_mfma_f32_16x16x16bf16_1k(ones4, pA, lAa, 0, 0, 0);
            lBa = __builtin_amdgcn_mfma_f32_16x16x16bf16_1k(ones4, pB, lBa, 0, 0, 0);
        }
    }
    float lA = lAa[0], lB = lBa[0];   // all rows identical (A = ones)
    float iA = 1.f / lA, iB = 1.f / lB;
    u16* oba = opb + (((size_t)(s * NB + b)) * NN + qa + c) * NC + h * HD;
    *(short4v*)&oba[u * 4]      = pack4(oA0[0] * iA, oA0[1] * iA, oA0[2] * iA, oA0[3] * iA);
    *(short4v*)&oba[16 + u * 4] = pack4(oA1[0] * iA, oA1[1] * iA, oA1[2] * iA, oA1[3] * iA);
    u16* obb = opb + (((size_t)(s * NB + b)) * NN + qbr + c) * NC + h * HD;
    *(short4v*)&obb[u * 4]      = pack4(oB0[0] * iB, oB0[1] * iB, oB0[2] * iB, oB0[3] * iB);
    *(short4v*)&obb[16 + u * 4] = pack4(oB1[0] * iB, oB1[1] * iB, oB1[2] * iB, oB1[3] * iB);
    if (u == 0) {
        lp[(((size_t)(s * NB + b)) * NHD + h) * NN + qa  + c] = lA;
        lp[(((size_t)(s * NB + b)) * NHD + h) * NN + qbr + c] = lB;
    }
}

// ---------------------------------------------------------------------------
// proj + LN via MFMA; 32 KB weight tile staged per block via global_load_lds.
// grid 392 x 256.
__global__ __launch_bounds__(256, 4) void k_proj2(const u16* __restrict__ opb,
                                                  const float* __restrict__ lp,
                                                  const u16* __restrict__ wps,
                                                  const float* __restrict__ bgb,
                                                  void* __restrict__ out,
                                                  const int* __restrict__ flag) {
    __shared__ __align__(16) u16 wl[16384];   // 32 KB staged weights
    __shared__ u16 Af[16 * 136];
    __shared__ float red1[4][16], red2[4][16];
    int bx = blockIdx.x;
    int b = bx >= 196;
    int n0 = (bx - b * 196) * 16;
    int t = threadIdx.x;
#pragma unroll
    for (int i = 0; i < 8; ++i)
        gld16(wps + (size_t)(i * 256 + t) * 8, wl + (size_t)(i * 256 + t) * 8);
    {   // combine: thread t -> row t>>4, channels (t&15)*8..+7
        int row = t >> 4, c8 = (t & 15) * 8;
        int n = n0 + row;
        int hh = c8 >> 5;
        float num[8] = {};
        float den = 0.f;
#pragma unroll
        for (int s = 0; s < NSPLIT; ++s) {
            float ls = lp[(((size_t)(s * NB + b)) * NHD + hh) * NN + n];
            short8 o8 = *(const short8*)&opb[(((size_t)(s * NB + b)) * NN + n) * NC + c8];
            den += ls;
#pragma unroll
            for (int i = 0; i < 8; ++i) num[i] += ls * b2f((u16)o8[i]);
        }
        float inv = 1.f / den;
        u16* dst = &Af[row * 136 + c8];
#pragma unroll
        for (int i = 0; i < 8; i += 2) {
            __hip_bfloat162 p = __float22bfloat162_rn(
                make_float2(num[i] * inv, num[i + 1] * inv));
            *(uint32_t*)&dst[i] = *(uint32_t*)&p;
        }
    }
    __syncthreads();   // drains weight staging + Af writes
    int w = t >> 6, lane = t & 63, c = lane & 15, u = lane >> 4;
    int oA = w * 32 + c, oB = w * 32 + 16 + c;
    const f32x4 z = {0.f, 0.f, 0.f, 0.f};
    f32x4 cA = z, cB = z;
#pragma unroll
    for (int kf = 0; kf < 4; ++kf) {
        short8 a  = *(const short8*)&Af[c * 136 + kf * 32 + u * 8];
        short8 bA = *(const short8*)&wl[(((2 * w) * 16 + kf * 4 + u) * 16 + c) * 8];
        short8 bB = *(const short8*)&wl[(((2 * w + 1) * 16 + kf * 4 + u) * 16 + c) * 8];
        cA = __builtin_amdgcn_mfma_f32_16x16x32_bf16(a, bA, cA, 0, 0, 0);
        cB = __builtin_amdgcn_mfma_f32_16x16x32_bf16(a, bB, cB, 0, 0, 0);
    }
    float bpA = bgb[oA], bpB = bgb[oB];
    float s1[4], s2[4];
#pragma unroll
    for (int r = 0; r < 4; ++r) {
        cA[r] += bpA; cB[r] += bpB;
        s1[r] = cA[r] + cB[r];
        s2[r] = cA[r] * cA[r] + cB[r] * cB[r];
    }
#pragma unroll
    for (int off = 1; off < 16; off <<= 1)
#pragma unroll
        for (int r = 0; r < 4; ++r) {
            s1[r] += __shfl_xor(s1[r], off);
            s2[r] += __shfl_xor(s2[r], off);
        }
    if (c == 0)
#pragma unroll
        for (int r = 0; r < 4; ++r) {
            red1[w][u * 4 + r] = s1[r];
            red2[w][u * 4 + r] = s2[r];
        }
    __syncthreads();
    float gA = bgb[128 + oA], beA = bgb[256 + oA];
    float gB = bgb[128 + oB], beB = bgb[256 + oB];
    float outA[4], outB[4];
#pragma unroll
    for (int r = 0; r < 4; ++r) {
        int row = u * 4 + r;
        float S1 = (red1[0][row] + red1[1][row]) + (red1[2][row] + red1[3][row]);
        float S2 = (red2[0][row] + red2[1][row]) + (red2[2][row] + red2[3][row]);
        float mu = S1 * (1.f / NC);
        float ex = S2 * (1.f / NC);
        float rstd = rsqrtf(ex - mu * mu + 1e-5f);
        outA[r] = (cA[r] - mu) * rstd * gA + beA;
        outB[r] = (cB[r] - mu) * rstd * gB + beB;
    }
    int n = n0 + u * 4;   // 4 consecutive rows per lane
    if (*flag) {
        __hip_bfloat16* ob = (__hip_bfloat16*)out;
        ushort4 sA = make_ushort4(bfb(outA[0]), bfb(outA[1]), bfb(outA[2]), bfb(outA[3]));
        ushort4 sB = make_ushort4(bfb(outB[0]), bfb(outB[1]), bfb(outB[2]), bfb(outB[3]));
        *(ushort4*)&ob[((size_t)(b * NC + oA)) * NN + n] = sA;
        *(ushort4*)&ob[((size_t)(b * NC + oB)) * NN + n] = sB;
    } else {
        float* ob = (float*)out;
        *(float4*)&ob[((size_t)(b * NC + oA)) * NN + n] = make_float4(outA[0], outA[1], outA[2], outA[3]);
        *(float4*)&ob[((size_t)(b * NC + oB)) * NN + n] = make_float4(outB[0], outB[1], outB[2], outB[3]);
    }
}

// ---------------------------------------------------------------------------
extern "C" void kernel_launch(void* const* d_in, const int* in_sizes, int n_in,
                              void* d_out, int out_size, void* d_ws, size_t ws_size,
                              hipStream_t stream) {
    const void* x_raw  = d_in[0];
    const void* wq_raw = d_in[1];
    const void* wp_raw = d_in[2];
    const void* bp_raw = d_in[3];
    const void* lg_raw = d_in[4];
    const void* lb_raw = d_in[5];

    int*   flag = (int*)d_ws;                           // 16 ints
    float* bgb  = (float*)d_ws + 16;                    // 512
    float* lp   = bgb + 512;                            // 4*2*4*3136
    u16*   opb  = (u16*)(lp + (size_t)NSPLIT * NB * NHD * NN);  // 4*2*3136*128
    u16*   wps  = opb + (size_t)NSPLIT * NB * NN * NC;  // 16384
    u16*   kbf  = wps + NC * NC;                        // 25 tiles x 4096 /bh
    u16*   vtb  = kbf + (size_t)NB * NHD * NTILE * 4096;
    u16*   qcb  = vtb + (size_t)NB * NHD * NTILE * 4096;
    u16*   agb  = qcb + (size_t)NB * NHD * NN * HD;     // 16384
    u16*   agT  = agb + NB * NHD * 64 * 32;             // 16384
    // total ~10.3 MB

    k_prep<<<145, 256, 0, stream>>>(x_raw, wp_raw, bp_raw, lg_raw, lb_raw,
                                    wps, bgb, agb, agT, flag);
    k_qkv_s1<<<dim3(NN / 64, 6, NB), 256, 0, stream>>>(x_raw, wq_raw, agb, agT,
                                                       kbf, vtb, qcb);
    k_flash4<<<dim3(25, NHD * NSPLIT, NB), 256, 0, stream>>>(qcb, kbf, vtb, opb, lp);
    k_proj2<<<392, 256, 0, stream>>>(opb, lp, wps, bgb, d_out, flag);
}